// Round 1
// 1324.840 us; speedup vs baseline: 1.1428x; 1.1428x over previous
//
#include <hip/hip_runtime.h>
#include <stdint.h>

#define HD 4096
#define TD 8192

typedef unsigned short u16;
typedef unsigned int u32;
typedef __bf16 bf16x8 __attribute__((ext_vector_type(8)));
typedef float f32x4 __attribute__((ext_vector_type(4)));

// async global->LDS, 16B per lane; LDS dest is wave-uniform base + lane*16,
// so lane l's global chunk must map to ldsbase + l*16 (layouts below do).
#define GL16(gp, lp) __builtin_amdgcn_global_load_lds( \
    (__attribute__((address_space(1))) void*)(void*)(uintptr_t)(gp), \
    (__attribute__((address_space(3))) void*)(lp), 16, 0, 0)

// ---------- NVFP4 quantization helpers ----------

// Round f (>=0) to nearest e4m3fn value (RTNE), returned as the decoded float.
__device__ __forceinline__ float e4m3_rtne(float f) {
  if (f <= 0.0f) return 0.0f;
  unsigned u = __float_as_uint(f);
  int e = (int)((u >> 23) & 0xff) - 127;
  if (e < -6) e = -6;
  float C = __uint_as_float((unsigned)(e + 147) << 23);  // 2^(e+20)
  float r = (f + C) - C;
  return fminf(r, 448.0f);
}

// Quantize 16 fp32 values (one NVFP4 block) with global scale g; write 16
// dequantized (q*s8 = dequant*g) values as bf16 bits (exact: <=6 sig bits).
__device__ __forceinline__ void quant_store16(const float v[16], float g, u16* dst) {
  float amax = 0.0f;
#pragma unroll
  for (int j = 0; j < 16; ++j) amax = fmaxf(amax, fabsf(v[j]));
  float s = e4m3_rtne(amax * g / 6.0f);
  u32 out[8];
  if (s > 0.0f) {
    const float m1 = 0.25f * s, m2 = 0.75f * s, m3 = 1.25f * s, m4 = 1.75f * s;
    const float m5 = 2.5f * s, m6 = 3.5f * s, m7 = 5.0f * s;
#pragma unroll
    for (int p = 0; p < 8; ++p) {
      u16 b[2];
#pragma unroll
      for (int h = 0; h < 2; ++h) {
        float t = v[2 * p + h] * g;
        float u = fabsf(t);
        float q = (u < m4) ? ((u < m2) ? ((u < m1) ? 0.0f : 0.5f)
                                       : ((u < m3) ? 1.0f : 1.5f))
                           : ((u < m6) ? ((u < m5) ? 2.0f : 3.0f)
                                       : ((u < m7) ? 4.0f : 6.0f));
        float val = copysignf(q * s, t);
        b[h] = (u16)(__float_as_uint(val) >> 16);  // exact bf16 truncation
      }
      out[p] = (u32)b[0] | ((u32)b[1] << 16);
    }
  } else {
#pragma unroll
    for (int p = 0; p < 8; ++p) out[p] = 0u;
  }
  uint4* d4 = (uint4*)dst;
  d4[0] = make_uint4(out[0], out[1], out[2], out[3]);
  d4[1] = make_uint4(out[4], out[5], out[6], out[7]);
}

__device__ __forceinline__ float block_sum256(float v) {
#pragma unroll
  for (int off = 32; off > 0; off >>= 1) v += __shfl_down(v, off, 64);
  __shared__ float red[4];
  int tid = threadIdx.x;
  if ((tid & 63) == 0) red[tid >> 6] = v;
  __syncthreads();
  return (red[0] + red[1]) + (red[2] + red[3]);
}

// ---------- elementwise / norm kernels (one block per row, 16 elem/thread) ----------

__global__ __launch_bounds__(256) void k_relu_norm_quant(
    const float* __restrict__ hs, const float* __restrict__ nw,
    const float* __restrict__ agp, float* __restrict__ resid,
    u16* __restrict__ yq) {
  const int row = blockIdx.x, tid = threadIdx.x;
  const size_t base = (size_t)row * HD + tid * 16;
  float v[16];
#pragma unroll
  for (int j = 0; j < 4; ++j) ((float4*)v)[j] = ((const float4*)(hs + base))[j];
  float ss = 0.0f;
#pragma unroll
  for (int j = 0; j < 16; ++j) {
    v[j] = fmaxf(v[j], 0.0f);
    ss += v[j] * v[j];
  }
#pragma unroll
  for (int j = 0; j < 4; ++j) ((float4*)(resid + base))[j] = ((float4*)v)[j];
  float tot = block_sum256(ss);
  float rs = 1.0f / sqrtf(tot * (1.0f / HD) + 1e-6f);
  const float* nwp = nw + tid * 16;  // norm_w[0]
  float y[16];
#pragma unroll
  for (int j = 0; j < 16; ++j) y[j] = v[j] * rs * nwp[j];
  quant_store16(y, agp[0], yq + base);
}

__global__ __launch_bounds__(256) void k_norm_quant(
    const float* __restrict__ resid, const float* __restrict__ nw,
    const float* __restrict__ agp, int li, u16* __restrict__ yq) {
  const int row = blockIdx.x, tid = threadIdx.x;
  const size_t base = (size_t)row * HD + tid * 16;
  float v[16];
#pragma unroll
  for (int j = 0; j < 4; ++j) ((float4*)v)[j] = ((const float4*)(resid + base))[j];
  float ss = 0.0f;
#pragma unroll
  for (int j = 0; j < 16; ++j) ss += v[j] * v[j];
  float tot = block_sum256(ss);
  float rs = 1.0f / sqrtf(tot * (1.0f / HD) + 1e-6f);
  const float* nwp = nw + (size_t)li * HD + tid * 16;
  float y[16];
#pragma unroll
  for (int j = 0; j < 16; ++j) y[j] = v[j] * rs * nwp[j];
  quant_store16(y, agp[li], yq + base);
}

__global__ __launch_bounds__(256) void k_final_norm(
    float* __restrict__ io, const float* __restrict__ nw) {
  const int row = blockIdx.x, tid = threadIdx.x;
  const size_t base = (size_t)row * HD + tid * 16;
  float v[16];
#pragma unroll
  for (int j = 0; j < 4; ++j) ((float4*)v)[j] = ((const float4*)(io + base))[j];
  float ss = 0.0f;
#pragma unroll
  for (int j = 0; j < 16; ++j) ss += v[j] * v[j];
  float tot = block_sum256(ss);
  float rs = 1.0f / sqrtf(tot * (1.0f / HD) + 1e-6f);
  const float* nwp = nw + (size_t)3 * HD + tid * 16;
#pragma unroll
  for (int j = 0; j < 16; ++j) v[j] = v[j] * rs * nwp[j];
#pragma unroll
  for (int j = 0; j < 4; ++j) ((float4*)(io + base))[j] = ((float4*)v)[j];
}

__global__ __launch_bounds__(256) void k_quant_w(
    const float* __restrict__ w, const float* __restrict__ wgp, int li,
    u16* __restrict__ wq) {
  const int row = blockIdx.x, tid = threadIdx.x;
  const size_t base = (size_t)li * HD * HD + (size_t)row * HD + tid * 16;
  float v[16];
#pragma unroll
  for (int j = 0; j < 4; ++j) ((float4*)v)[j] = ((const float4*)(w + base))[j];
  quant_store16(v, wgp[li], wq + (size_t)row * HD + tid * 16);
}

// ---------- bf16 GEMM, 256x256 8-phase schedule: z = A @ B^T, resid += z*alpha ----------
// A [TD, HD] bf16 bits, B [HD, HD] bf16 bits (B row = output col).
// BM=BN=256, BK=64. 8 waves = 2(M) x 4(N); per-wave output 128x64 = 8x4
// mfma_f32_16x16x32_bf16 frags. LDS: 2 buffers x [256 rows][64] bf16 per
// operand = 128 KiB. buf0 holds even K-tiles, buf1 odd (fixed roles).
//
// Swizzle (both-sides, rule #21): 16B chunk kc of row m lives at LDS chunk
// kc ^ (m&7); staging keeps LDS linear and pre-swizzles the GLOBAL source
// column; ds_read_b128 applies the same XOR. Frag reads are then
// bank-optimal (each 16-lane group covers all 8 chunk-columns).
//
// Phase schedule per iteration (2 K-tiles: 2i in buf0, 2i+1 in buf1).
// Reads (ds_read_b128): ph1: buf0 A-mh0(8) + B-all(8); ph3: buf0 A-mh1(8);
// ph5/ph7 same on buf1. Region last-read (across all waves, barriers keep
// phases in lockstep): buf0.B* -> ph1, buf0.A* -> ph3 (mh0 rows of wr=1 and
// mh1 rows of wr=0 both land in the "other" 128-row half). Stage slots
// (1 half-tile = 2 global_load_lds per thread, per phase):
//   ph1: buf1.A1[t=2i+1]   (region free since prev ph7; completes buf1)
//   ph2: buf0.B0[t=2i+2]   ph3: buf0.B1   ph4: buf0.A0   ph5: buf0.A1
//   ph6: buf1.B0[t=2i+3]   ph7: buf1.B1   ph8: buf1.A0
// Counted vmcnt(6) (=3 half-tiles in flight) at ph4 and ph8 only:
//   ph4 wait leaves {ph2,ph3,ph4} outstanding -> forces ph1's buf1.A1 and
//   prev-iter ph6-8 landed before ph5 reads buf1.
//   ph8 wait leaves {ph6,ph7,ph8} outstanding -> forces ph2-ph5 (all of
//   buf0, tile 2i+2) landed before next-iter ph1 reads buf0.
// Last iteration's ph2-8 stages wrap to tiles 0/1 (harmless refetch, keeps
// vmcnt counts uniform). Accumulation order over K is identical to the old
// kernel (tile-major, kk 0 then 1) -> bit-identical results.

#define BARF() do { asm volatile("" ::: "memory"); \
    __builtin_amdgcn_s_barrier(); \
    asm volatile("" ::: "memory"); } while (0)
#define WLG() asm volatile("s_waitcnt lgkmcnt(0)" ::: "memory")
#define WVM6() asm volatile("s_waitcnt vmcnt(6)" ::: "memory")

__global__ __launch_bounds__(512, 2) void k_gemm(
    const u16* __restrict__ A, const u16* __restrict__ B,
    float* __restrict__ resid, const float* __restrict__ agp,
    const float* __restrict__ wgp, int layer) {
  __shared__ __align__(16) u16 ldsA[2 * 256 * 64];  // [buf][row][64]
  __shared__ __align__(16) u16 ldsB[2 * 256 * 64];
  const int tid = threadIdx.x;
  const int lane = tid & 63, wave = tid >> 6;
  const int wr = wave >> 2, wc = wave & 3;     // 2 x 4 wave grid
  const int r = lane & 15, q = lane >> 4;

  int bid = blockIdx.x;
  bid = (bid & 7) * 64 + (bid >> 3);  // XCD-contiguous chunks (512 % 8 == 0)
  const int m0 = (bid >> 4) * 256;
  const int n0 = (bid & 15) * 256;

  // ---- staging constants: chunk c=tid (+512) -> lds half-tile byte c*16;
  // global row = half*128 + (c>>3), colchunk = (c&7) ^ ((c>>3)&7).
  const int rs = tid >> 3;
  const int cs = ((tid & 7) ^ (rs & 7)) * 8;
  const u16* gA = A + (size_t)(m0 + rs) * HD + cs;
  const u16* gB = B + (size_t)(n0 + rs) * HD + cs;
  u16* lA = ldsA + tid * 8;
  u16* lB = ldsB + tid * 8;

#define STG_A(bb, h, koff) do { \
    GL16(gA + (size_t)(h) * (128 * HD) + (koff), lA + (bb) + (h) * 8192); \
    GL16(gA + (size_t)(h) * (128 * HD) + 64 * HD + (koff), lA + (bb) + (h) * 8192 + 4096); \
  } while (0)
#define STG_B(bb, h, koff) do { \
    GL16(gB + (size_t)(h) * (128 * HD) + (koff), lB + (bb) + (h) * 8192); \
    GL16(gB + (size_t)(h) * (128 * HD) + 64 * HD + (koff), lB + (bb) + (h) * 8192 + 4096); \
  } while (0)

  // ---- fragment-read constants (element offsets into a 256x64 buffer)
  const int sa = (q ^ (r & 7)) * 8;        // kk=0 swizzled chunk
  const int sb = ((q + 4) ^ (r & 7)) * 8;  // kk=1
  const int arow = (wr * 128 + r) * 64;
  const int brow = (wc * 64 + r) * 64;

  f32x4 acc[8][4];
#pragma unroll
  for (int i = 0; i < 8; ++i)
#pragma unroll
    for (int j = 0; j < 4; ++j) acc[i][j] = (f32x4){0.f, 0.f, 0.f, 0.f};

  bf16x8 a[4][2], b[4][2];

#define LD_A(base) do { \
    _Pragma("unroll") \
    for (int mi = 0; mi < 4; ++mi) { \
      a[mi][0] = *(const bf16x8*)((base) + arow + mi * 1024 + sa); \
      a[mi][1] = *(const bf16x8*)((base) + arow + mi * 1024 + sb); \
    } } while (0)
#define LD_B(base) do { \
    _Pragma("unroll") \
    for (int nj = 0; nj < 4; ++nj) { \
      b[nj][0] = *(const bf16x8*)((base) + brow + nj * 1024 + sa); \
      b[nj][1] = *(const bf16x8*)((base) + brow + nj * 1024 + sb); \
    } } while (0)
#define MMQ(mh, nh) do { \
    _Pragma("unroll") \
    for (int mi = 0; mi < 4; ++mi) \
    _Pragma("unroll") \
    for (int nj = 0; nj < 2; ++nj) { \
      acc[(mh) * 4 + mi][(nh) * 2 + nj] = __builtin_amdgcn_mfma_f32_16x16x32_bf16( \
          a[mi][0], b[(nh) * 2 + nj][0], acc[(mh) * 4 + mi][(nh) * 2 + nj], 0, 0, 0); \
      acc[(mh) * 4 + mi][(nh) * 2 + nj] = __builtin_amdgcn_mfma_f32_16x16x32_bf16( \
          a[mi][1], b[(nh) * 2 + nj][1], acc[(mh) * 4 + mi][(nh) * 2 + nj], 0, 0, 0); \
    } } while (0)

  // ---- prologue: tile0 -> buf0 (all 4 half-tiles), tile1 -> buf1 (B0,B1,A0).
  // vmcnt(6) forces exactly the 8 buf0 loads landed; buf1's 6 stay in flight.
  STG_B(0, 0, 0); STG_B(0, 1, 0);
  STG_A(0, 0, 0); STG_A(0, 1, 0);
  STG_B(16384, 0, 64); STG_B(16384, 1, 64);
  STG_A(16384, 0, 64);
  WVM6();
  BARF();

  for (int i = 0; i < 32; ++i) {
    const int kb = i * 128;
    const int k1 = kb + 64;                       // tile 2i+1 (never wraps)
    int k2 = kb + 128; if (k2 >= HD) k2 -= HD;    // tile 2i+2 (wrap last iter)
    int k3 = kb + 192; if (k3 >= HD) k3 -= HD;    // tile 2i+3
    // ph1: buf0 Q(mh0,nh0); stage buf1.A1[2i+1]
    LD_A(ldsA); LD_B(ldsB);
    STG_A(16384, 1, k1);
    BARF(); WLG();
    __builtin_amdgcn_s_setprio(1); MMQ(0, 0); __builtin_amdgcn_s_setprio(0);
    BARF();
    // ph2: Q(mh0,nh1); stage buf0.B0[2i+2]
    STG_B(0, 0, k2);
    BARF();
    __builtin_amdgcn_s_setprio(1); MMQ(0, 1); __builtin_amdgcn_s_setprio(0);
    BARF();
    // ph3: Q(mh1,nh0); stage buf0.B1
    LD_A(ldsA + 4096);
    STG_B(0, 1, k2);
    BARF(); WLG();
    __builtin_amdgcn_s_setprio(1); MMQ(1, 0); __builtin_amdgcn_s_setprio(0);
    BARF();
    // ph4: Q(mh1,nh1); stage buf0.A0; counted vmcnt -> buf1 fully landed
    STG_A(0, 0, k2);
    WVM6();
    BARF();
    __builtin_amdgcn_s_setprio(1); MMQ(1, 1); __builtin_amdgcn_s_setprio(0);
    BARF();
    // ph5: buf1 Q(mh0,nh0); stage buf0.A1
    LD_A(ldsA + 16384); LD_B(ldsB + 16384);
    STG_A(0, 1, k2);
    BARF(); WLG();
    __builtin_amdgcn_s_setprio(1); MMQ(0, 0); __builtin_amdgcn_s_setprio(0);
    BARF();
    // ph6: Q(mh0,nh1); stage buf1.B0[2i+3]
    STG_B(16384, 0, k3);
    BARF();
    __builtin_amdgcn_s_setprio(1); MMQ(0, 1); __builtin_amdgcn_s_setprio(0);
    BARF();
    // ph7: Q(mh1,nh0); stage buf1.B1
    LD_A(ldsA + 16384 + 4096);
    STG_B(16384, 1, k3);
    BARF(); WLG();
    __builtin_amdgcn_s_setprio(1); MMQ(1, 0); __builtin_amdgcn_s_setprio(0);
    BARF();
    // ph8: Q(mh1,nh1); stage buf1.A0; counted vmcnt -> buf0 fully landed
    STG_A(16384, 0, k3);
    WVM6();
    BARF();
    __builtin_amdgcn_s_setprio(1); MMQ(1, 1); __builtin_amdgcn_s_setprio(0);
    BARF();
  }

  const float alpha = 1.0f / (agp[layer] * wgp[layer]);
  // C/D layout: col = lane&15 (n), row = (lane>>4)*4 + reg (m)
#pragma unroll
  for (int mi = 0; mi < 8; ++mi) {
    const int gm0 = m0 + wr * 128 + mi * 16 + q * 4;
#pragma unroll
    for (int nj = 0; nj < 4; ++nj) {
      const int gn = n0 + wc * 64 + nj * 16 + r;
#pragma unroll
      for (int t = 0; t < 4; ++t) {
        float* p = resid + (size_t)(gm0 + t) * HD + gn;
        *p = fmaf(acc[mi][nj][t], alpha, *p);
      }
    }
  }
}

// ---------- host ----------

extern "C" void kernel_launch(void* const* d_in, const int* in_sizes, int n_in,
                              void* d_out, int out_size, void* d_ws, size_t ws_size,
                              hipStream_t stream) {
  const float* hs = (const float*)d_in[0];
  const float* nw = (const float*)d_in[1];
  const float* w = (const float*)d_in[2];
  const float* ag = (const float*)d_in[3];
  const float* wg = (const float*)d_in[4];
  float* out = (float*)d_out;  // fp32 resid scratch; final y overwrites in place

  u16* wq = (u16*)d_ws;                    // HD*HD bf16 bits (32 MiB), reused per layer
  u16* yq = (u16*)d_ws + (size_t)HD * HD;  // TD*HD bf16 bits (64 MiB)

  k_relu_norm_quant<<<TD, 256, 0, stream>>>(hs, nw, ag, out, yq);
  for (int l = 0; l < 3; ++l) {
    k_quant_w<<<HD, 256, 0, stream>>>(w, wg, l, wq);
    k_gemm<<<dim3((TD / 256) * (HD / 256)), 512, 0, stream>>>(yq, wq, out, ag, wg, l);
    if (l < 2) k_norm_quant<<<TD, 256, 0, stream>>>(out, nw, ag, l + 1, yq);
  }
  k_final_norm<<<TD, 256, 0, stream>>>(out, nw);
}